// Round 7
// baseline (709.247 us; speedup 1.0000x reference)
//
#include <hip/hip_runtime.h>

#define BB 4
#define SS 2048
#define DDIM 512
#define HH 8
#define MTOK (BB*SS)   // 8192
#define BHN (BB*HH)    // 32

typedef _Float16 f16;
typedef __attribute__((ext_vector_type(8))) _Float16 half8;
typedef __attribute__((ext_vector_type(4))) _Float16 half4;
typedef __attribute__((ext_vector_type(4))) float float4v;
typedef __attribute__((ext_vector_type(4))) int int4v;

#define SCALE_L2E 0.180336880073616f   // 0.125 * log2(e)
#define L2E 1.44269504088896f
#define EBIAS 4.0f                     // E = exp2(s*log2e - EBIAS); cancels in softmax

__device__ __forceinline__ float4v mfma_k32(half8 a, half8 b, float4v c) {
  return __builtin_amdgcn_mfma_f32_16x16x32_f16(a, b, c, 0, 0, 0);
}
__device__ __forceinline__ float4v mfma_k16(half4 a, half4 b, float4v c) {
  return __builtin_amdgcn_mfma_f32_16x16x16f16(a, b, c, 0, 0, 0);
}

__device__ __forceinline__ half8 cvt8(float4v a, float4v b) {
  half8 r;
  r[0] = (f16)a[0]; r[1] = (f16)a[1]; r[2] = (f16)a[2]; r[3] = (f16)a[3];
  r[4] = (f16)b[0]; r[5] = (f16)b[1]; r[6] = (f16)b[2]; r[7] = (f16)b[3];
  return r;
}

// ---------------- mask dtype detection ----------------
__global__ __launch_bounds__(256) void detect_mask_kernel(
    const unsigned int* __restrict__ m, unsigned int* __restrict__ flag) {
  unsigned int v = 0;
  const int base = blockIdx.x * 1024;
  for (int j = threadIdx.x; j < 1024; j += 256)
    if (m[base + j] > 1u) v = 1u;
  if (v) atomicOr(flag, 1u);
}

// ---------------- batched QKV projection ----------------
// z=0: Qp [tok][512] f16; z=1: Kpk [bh][tok][64]; z=2: Vtt [bh][dv][tok].
__global__ __launch_bounds__(256) void gemm_qkv(
    const float* __restrict__ inQ, const float* __restrict__ inK,
    const float* __restrict__ inV, const float* __restrict__ WQ,
    const float* __restrict__ WK, const float* __restrict__ WV,
    f16* __restrict__ Qp, f16* __restrict__ Kpk, f16* __restrict__ Vtt) {
  __shared__ f16 As[128][40];
  __shared__ f16 Bs[128][40];
  const int z = blockIdx.z;
  const float* A = (z == 0) ? inQ : (z == 1) ? inK : inV;
  const float* W = (z == 0) ? WQ : (z == 1) ? WK : WV;
  const int t = threadIdx.x;
  const int bm = blockIdx.x * 128;
  const int bn = blockIdx.y * 128;
  const int w = t >> 6, ln = t & 63;
  const int wr = w >> 1, wc = w & 1;
  const int lr = ln & 15, lg = ln >> 4;
  const int srow = t >> 1, scol = (t & 1) * 16;

  float4v acc[4][4] = {};

  for (int k0 = 0; k0 < 512; k0 += 32) {
    {
      const float* ap = A + (size_t)(bm + srow) * 512 + k0 + scol;
      float4v x0 = *(const float4v*)ap,       x1 = *(const float4v*)(ap + 4);
      float4v x2 = *(const float4v*)(ap + 8), x3 = *(const float4v*)(ap + 12);
      *(half8*)&As[srow][scol]     = cvt8(x0, x1);
      *(half8*)&As[srow][scol + 8] = cvt8(x2, x3);
    }
    {
      const float* wp = W + (size_t)(bn + srow) * 512 + k0 + scol;
      float4v x0 = *(const float4v*)wp,       x1 = *(const float4v*)(wp + 4);
      float4v x2 = *(const float4v*)(wp + 8), x3 = *(const float4v*)(wp + 12);
      *(half8*)&Bs[srow][scol]     = cvt8(x0, x1);
      *(half8*)&Bs[srow][scol + 8] = cvt8(x2, x3);
    }
    __syncthreads();
    half8 af[4], bf[4];
    #pragma unroll
    for (int m = 0; m < 4; m++) af[m] = *(const half8*)&As[wr * 64 + m * 16 + lr][lg * 8];
    #pragma unroll
    for (int n = 0; n < 4; n++) bf[n] = *(const half8*)&Bs[wc * 64 + n * 16 + lr][lg * 8];
    #pragma unroll
    for (int m = 0; m < 4; m++)
      #pragma unroll
      for (int n = 0; n < 4; n++) acc[m][n] = mfma_k32(af[m], bf[n], acc[m][n]);
    __syncthreads();
  }

  #pragma unroll
  for (int m = 0; m < 4; m++) {
    int row = bm + wr * 64 + m * 16 + lg * 4;
    #pragma unroll
    for (int n = 0; n < 4; n++) {
      int col = bn + wc * 64 + n * 16 + lr;
      int b_ = row >> 11, s_ = row & 2047, h_ = col >> 6, d_ = col & 63;
      if (z == 0) {
        #pragma unroll
        for (int r = 0; r < 4; r++)
          Qp[(size_t)(row + r) * 512 + col] = (f16)acc[m][n][r];
      } else if (z == 1) {
        #pragma unroll
        for (int r = 0; r < 4; r++)
          Kpk[(((size_t)(b_ * 8 + h_)) * SS + s_ + r) * 64 + d_] = (f16)acc[m][n][r];
      } else {
        half4 ph;
        ph[0] = (f16)acc[m][n][0]; ph[1] = (f16)acc[m][n][1];
        ph[2] = (f16)acc[m][n][2]; ph[3] = (f16)acc[m][n][3];
        *(half4*)&Vtt[(((size_t)(b_ * 8 + h_)) * 64 + d_) * SS + s_] = ph;
      }
    }
  }
}

// ---------------- output GEMM: ctx (f16) x W_fc^T -> fp32 ----------------
__global__ __launch_bounds__(256) void gemm_out(const f16* __restrict__ ctx,
                                                const float* __restrict__ W,
                                                float* __restrict__ Out) {
  __shared__ f16 As[128][40];
  __shared__ f16 Bs[128][40];
  const int t = threadIdx.x;
  const int bm = blockIdx.x * 128;
  const int bn = blockIdx.y * 128;
  const int w = t >> 6, ln = t & 63;
  const int wr = w >> 1, wc = w & 1;
  const int lr = ln & 15, lg = ln >> 4;
  const int srow = t >> 1, scol = (t & 1) * 16;

  float4v acc[4][4] = {};

  for (int k0 = 0; k0 < 512; k0 += 32) {
    {
      const f16* ap = ctx + (size_t)(bm + srow) * 512 + k0 + scol;
      *(half8*)&As[srow][scol]     = *(const half8*)(ap);
      *(half8*)&As[srow][scol + 8] = *(const half8*)(ap + 8);
    }
    {
      const float* wp = W + (size_t)(bn + srow) * 512 + k0 + scol;
      float4v x0 = *(const float4v*)wp,       x1 = *(const float4v*)(wp + 4);
      float4v x2 = *(const float4v*)(wp + 8), x3 = *(const float4v*)(wp + 12);
      *(half8*)&Bs[srow][scol]     = cvt8(x0, x1);
      *(half8*)&Bs[srow][scol + 8] = cvt8(x2, x3);
    }
    __syncthreads();
    half8 af[4], bf[4];
    #pragma unroll
    for (int m = 0; m < 4; m++) af[m] = *(const half8*)&As[wr * 64 + m * 16 + lr][lg * 8];
    #pragma unroll
    for (int n = 0; n < 4; n++) bf[n] = *(const half8*)&Bs[wc * 64 + n * 16 + lr][lg * 8];
    #pragma unroll
    for (int m = 0; m < 4; m++)
      #pragma unroll
      for (int n = 0; n < 4; n++) acc[m][n] = mfma_k32(af[m], bf[n], acc[m][n]);
    __syncthreads();
  }

  #pragma unroll
  for (int m = 0; m < 4; m++) {
    int row = bm + wr * 64 + m * 16 + lg * 4;
    #pragma unroll
    for (int n = 0; n < 4; n++) {
      int col = bn + wc * 64 + n * 16 + lr;
      #pragma unroll
      for (int r = 0; r < 4; r++)
        Out[(size_t)(row + r) * 512 + col] = acc[m][n][r];
    }
  }
}

// ---------------- single fused attention kernel ----------------
// Block = (b, 16 q-rows), 512 threads (8 waves), each wave owns a 32-wide
// k-slice per 256-k step.  h outer, kt inner.  Per head:
//   pass 1 (no barriers): QK^T (transposed) -> +other/mask (direct, L2-hot
//     across heads) -> exp2 -> E kept in 32 VGPRs (16 x half4) + row-sum +
//     UNNORMALIZED PV: E's register layout IS the 16x16x16 A-operand, so PV
//     accumulates from registers (no LDS, no shuffle).
//   barrier; cross-wave reduce of row-sums + PV partials via LDS;
//   pass 2: attn = E*invl (full-line nontemporal float4), ctx = cacc*invl.
// 2 barriers per head.  bid&7 -> one b per XCD (K+V slice 4 MB in its L2).
__global__ __launch_bounds__(512, 4) void attn_fused1(
    const f16* __restrict__ Qp, const f16* __restrict__ Kpk,
    const f16* __restrict__ Vtt, const float* __restrict__ other,
    const unsigned char* __restrict__ mask8, const int* __restrict__ mask32,
    const unsigned int* __restrict__ flag, float* __restrict__ attn_out,
    f16* __restrict__ ctx) {
  __shared__ float red[8][16];        // [wave][q] row-sum partials
  __shared__ float red2[8][16][65];   // [wave][q][dv] PV partials (+pad)

  const int t = threadIdx.x;
  const int bid = blockIdx.x;
  const int b = bid & 3;
  const int qblk = (bid >> 2) * 16;
  const int w = t >> 6, ln = t & 63;
  const int lr = ln & 15, lg = ln >> 4;
  const bool use8 = (*flag) != 0;
  const int q_g = qblk + lr;
  const size_t orow = ((size_t)b * SS + q_g) * SS;

  for (int h = 0; h < 8; h++) {
    const int bh = b * 8 + h;
    // Q fragment (B-operand: col=q=lr, k=lg*8..)
    const f16* qp = Qp + ((size_t)b * SS + q_g) * 512 + h * 64 + lg * 8;
    const half8 qf0 = *(const half8*)qp;
    const half8 qf1 = *(const half8*)(qp + 32);

    half4 eh[16];          // E regs: [kt][n]
    float rs = 0.f;
    float4v cacc[4] = {};  // PV partials, dv-tiles (unnormalized)

    #pragma unroll
    for (int kt = 0; kt < 8; kt++) {
      const int kb = kt * 256 + w * 32;
      // K fragments (A-operand rows = k tokens, wave-disjoint)
      const f16* kp = Kpk + ((size_t)bh * SS + kb + lr) * 64 + lg * 8;
      const half8 kf00 = *(const half8*)(kp);
      const half8 kf01 = *(const half8*)(kp + 32);
      const half8 kf10 = *(const half8*)(kp + 1024);       // +16 tokens
      const half8 kf11 = *(const half8*)(kp + 1024 + 32);
      float4v s0 = {}, s1 = {};
      s0 = mfma_k32(kf00, qf0, s0);
      s0 = mfma_k32(kf01, qf1, s0);
      s1 = mfma_k32(kf10, qf0, s1);
      s1 = mfma_k32(kf11, qf1, s1);
      #pragma unroll
      for (int n = 0; n < 2; n++) {
        const float4v sv = n ? s1 : s0;
        const int k0 = kb + n * 16 + lg * 4;
        float4v oth = *(const float4v*)&other[orow + k0];
        float4v ev;
        if (use8) {
          unsigned int mwb = *(const unsigned int*)&mask8[orow + k0];
          #pragma unroll
          for (int r = 0; r < 4; r++) {
            float o2 = ((mwb >> (8 * r)) & 0xffu) ? -1e9f
                                                  : fmaf(oth[r], L2E, -EBIAS);
            ev[r] = exp2f(fmaf(sv[r], SCALE_L2E, o2));
          }
        } else {
          int4v mw4 = *(const int4v*)&mask32[orow + k0];
          #pragma unroll
          for (int r = 0; r < 4; r++) {
            float o2 = mw4[r] ? -1e9f : fmaf(oth[r], L2E, -EBIAS);
            ev[r] = exp2f(fmaf(sv[r], SCALE_L2E, o2));
          }
        }
        rs += (ev[0] + ev[1]) + (ev[2] + ev[3]);
        half4 pa;
        pa[0] = (f16)ev[0]; pa[1] = (f16)ev[1];
        pa[2] = (f16)ev[2]; pa[3] = (f16)ev[3];
        eh[kt * 2 + n] = pa;
        // PV: pa is directly the 16x16x16 A-operand (row=q=lr, k=lg*4+r)
        const f16* vp = Vtt + ((size_t)bh * 64 + lr) * SS + k0;
        #pragma unroll
        for (int n2 = 0; n2 < 4; n2++) {
          half4 vf = *(const half4*)(vp + (size_t)n2 * 16 * SS);
          cacc[n2] = mfma_k16(pa, vf, cacc[n2]);
        }
      }
    }
    // ---- cross-wave reductions ----
    float v = rs;
    v += __shfl_xor(v, 16);
    v += __shfl_xor(v, 32);
    if (ln < 16) red[w][lr] = v;
    #pragma unroll
    for (int n2 = 0; n2 < 4; n2++)
      #pragma unroll
      for (int r = 0; r < 4; r++)
        red2[w][lg * 4 + r][n2 * 16 + lr] = cacc[n2][r];
    __syncthreads();
    // ---- pass 2: attn stores ----
    float l_a = 0.f;
    #pragma unroll
    for (int ww = 0; ww < 8; ww++) l_a += red[ww][lr];
    const float invla = 1.0f / l_a;
    #pragma unroll
    for (int kt = 0; kt < 8; kt++) {
      #pragma unroll
      for (int n = 0; n < 2; n++) {
        const int k0 = kt * 256 + w * 32 + n * 16 + lg * 4;
        const half4 e4 = eh[kt * 2 + n];
        float4v av;
        av[0] = (float)e4[0] * invla; av[1] = (float)e4[1] * invla;
        av[2] = (float)e4[2] * invla; av[3] = (float)e4[3] * invla;
        __builtin_nontemporal_store(
            av, (float4v*)&attn_out[((size_t)bh * SS + q_g) * SS + k0]);
      }
    }
    // ---- ctx: sum 8 wave-partials, normalize, store ----
    {
      const int q = t >> 5;           // 0..15
      const int dv0 = (t & 31) * 2;   // 0..62
      float l_c = 0.f, c0 = 0.f, c1 = 0.f;
      #pragma unroll
      for (int ww = 0; ww < 8; ww++) {
        l_c += red[ww][q];
        c0 += red2[ww][q][dv0];
        c1 += red2[ww][q][dv0 + 1];
      }
      const float invc = 1.0f / l_c;
      f16* cp = ctx + ((size_t)b * SS + qblk + q) * 512 + h * 64 + dv0;
      cp[0] = (f16)(c0 * invc);
      cp[1] = (f16)(c1 * invc);
    }
    __syncthreads();  // red/red2 reused next head
  }
}

extern "C" void kernel_launch(void* const* d_in, const int* in_sizes, int n_in,
                              void* d_out, int out_size, void* d_ws, size_t ws_size,
                              hipStream_t stream) {
  const float* inQ   = (const float*)d_in[0];
  const float* inK   = (const float*)d_in[1];
  const float* inV   = (const float*)d_in[2];
  const void*  mask  = d_in[3];
  const float* other = (const float*)d_in[4];
  const float* WQ    = (const float*)d_in[5];
  const float* WK    = (const float*)d_in[6];
  const float* WV    = (const float*)d_in[7];
  const float* WF    = (const float*)d_in[8];

  char* ws = (char*)d_ws;
  size_t off = 0;
  unsigned int* flag = (unsigned int*)(ws + off); off += 256;
  f16* Qp  = (f16*)(ws + off); off += (size_t)MTOK * 512 * 2;
  f16* Kpk = (f16*)(ws + off); off += (size_t)MTOK * 512 * 2;
  f16* Vtt = (f16*)(ws + off); off += (size_t)MTOK * 512 * 2;
  f16* ctx = (f16*)(ws + off); off += (size_t)MTOK * 512 * 2;
  if (ws_size < off) return;

  float* outp  = (float*)d_out;
  float* attnp = outp + (size_t)MTOK * DDIM;

  hipMemsetAsync(flag, 0, 256, stream);
  detect_mask_kernel<<<64, 256, 0, stream>>>((const unsigned int*)mask, flag);

  gemm_qkv<<<dim3(64, 4, 3), 256, 0, stream>>>(inQ, inK, inV, WQ, WK, WV,
                                               Qp, Kpk, Vtt);

  attn_fused1<<<512, 512, 0, stream>>>(
      Qp, Kpk, Vtt, other, (const unsigned char*)mask, (const int*)mask, flag,
      attnp, ctx);

  gemm_out<<<dim3(64, 4), 256, 0, stream>>>(ctx, WF, outp);
}

// Round 8
// 625.782 us; speedup vs baseline: 1.1334x; 1.1334x over previous
//
#include <hip/hip_runtime.h>

#define BB 4
#define SS 2048
#define DDIM 512
#define HH 8
#define MTOK (BB*SS)   // 8192
#define BHN (BB*HH)    // 32

typedef _Float16 f16;
typedef __attribute__((ext_vector_type(8))) _Float16 half8;
typedef __attribute__((ext_vector_type(4))) _Float16 half4;
typedef __attribute__((ext_vector_type(4))) float float4v;
typedef __attribute__((ext_vector_type(4))) int int4v;
typedef __attribute__((ext_vector_type(4))) unsigned int uint4v;

#define SCALE_L2E 0.180336880073616f   // 0.125 * log2(e)
#define L2E 1.44269504088896f
#define EBIAS 4.0f                     // cancels in softmax; f16 overflow headroom
#define MASKVAL -65504.0f              // f16 -max; exp2 -> 0

__device__ __forceinline__ float4v mfma_k32(half8 a, half8 b, float4v c) {
  return __builtin_amdgcn_mfma_f32_16x16x32_f16(a, b, c, 0, 0, 0);
}
__device__ __forceinline__ float4v mfma_k16(half4 a, half4 b, float4v c) {
  return __builtin_amdgcn_mfma_f32_16x16x16f16(a, b, c, 0, 0, 0);
}

__device__ __forceinline__ half8 cvt8(float4v a, float4v b) {
  half8 r;
  r[0] = (f16)a[0]; r[1] = (f16)a[1]; r[2] = (f16)a[2]; r[3] = (f16)a[3];
  r[4] = (f16)b[0]; r[5] = (f16)b[1]; r[6] = (f16)b[2]; r[7] = (f16)b[3];
  return r;
}

// ---------------- mask dtype detection ----------------
__global__ __launch_bounds__(256) void detect_mask_kernel(
    const unsigned int* __restrict__ m, unsigned int* __restrict__ flag) {
  unsigned int v = 0;
  const int base = blockIdx.x * 1024;
  for (int j = threadIdx.x; j < 1024; j += 256)
    if (m[base + j] > 1u) v = 1u;
  if (v) atomicOr(flag, 1u);
}

// ---------------- batched QKV projection ----------------
// z=0: Qp [tok][512] f16; z=1: Kpk [bh][tok][64]; z=2: Vtt [bh][dv][tok].
__global__ __launch_bounds__(256) void gemm_qkv(
    const float* __restrict__ inQ, const float* __restrict__ inK,
    const float* __restrict__ inV, const float* __restrict__ WQ,
    const float* __restrict__ WK, const float* __restrict__ WV,
    f16* __restrict__ Qp, f16* __restrict__ Kpk, f16* __restrict__ Vtt) {
  __shared__ f16 As[128][40];
  __shared__ f16 Bs[128][40];
  const int z = blockIdx.z;
  const float* A = (z == 0) ? inQ : (z == 1) ? inK : inV;
  const float* W = (z == 0) ? WQ : (z == 1) ? WK : WV;
  const int t = threadIdx.x;
  const int bm = blockIdx.x * 128;
  const int bn = blockIdx.y * 128;
  const int w = t >> 6, ln = t & 63;
  const int wr = w >> 1, wc = w & 1;
  const int lr = ln & 15, lg = ln >> 4;
  const int srow = t >> 1, scol = (t & 1) * 16;

  float4v acc[4][4] = {};

  for (int k0 = 0; k0 < 512; k0 += 32) {
    {
      const float* ap = A + (size_t)(bm + srow) * 512 + k0 + scol;
      float4v x0 = *(const float4v*)ap,       x1 = *(const float4v*)(ap + 4);
      float4v x2 = *(const float4v*)(ap + 8), x3 = *(const float4v*)(ap + 12);
      *(half8*)&As[srow][scol]     = cvt8(x0, x1);
      *(half8*)&As[srow][scol + 8] = cvt8(x2, x3);
    }
    {
      const float* wp = W + (size_t)(bn + srow) * 512 + k0 + scol;
      float4v x0 = *(const float4v*)wp,       x1 = *(const float4v*)(wp + 4);
      float4v x2 = *(const float4v*)(wp + 8), x3 = *(const float4v*)(wp + 12);
      *(half8*)&Bs[srow][scol]     = cvt8(x0, x1);
      *(half8*)&Bs[srow][scol + 8] = cvt8(x2, x3);
    }
    __syncthreads();
    half8 af[4], bf[4];
    #pragma unroll
    for (int m = 0; m < 4; m++) af[m] = *(const half8*)&As[wr * 64 + m * 16 + lr][lg * 8];
    #pragma unroll
    for (int n = 0; n < 4; n++) bf[n] = *(const half8*)&Bs[wc * 64 + n * 16 + lr][lg * 8];
    #pragma unroll
    for (int m = 0; m < 4; m++)
      #pragma unroll
      for (int n = 0; n < 4; n++) acc[m][n] = mfma_k32(af[m], bf[n], acc[m][n]);
    __syncthreads();
  }

  #pragma unroll
  for (int m = 0; m < 4; m++) {
    int row = bm + wr * 64 + m * 16 + lg * 4;
    #pragma unroll
    for (int n = 0; n < 4; n++) {
      int col = bn + wc * 64 + n * 16 + lr;
      int b_ = row >> 11, s_ = row & 2047, h_ = col >> 6, d_ = col & 63;
      if (z == 0) {
        #pragma unroll
        for (int r = 0; r < 4; r++)
          Qp[(size_t)(row + r) * 512 + col] = (f16)acc[m][n][r];
      } else if (z == 1) {
        #pragma unroll
        for (int r = 0; r < 4; r++)
          Kpk[(((size_t)(b_ * 8 + h_)) * SS + s_ + r) * 64 + d_] = (f16)acc[m][n][r];
      } else {
        half4 ph;
        ph[0] = (f16)acc[m][n][0]; ph[1] = (f16)acc[m][n][1];
        ph[2] = (f16)acc[m][n][2]; ph[3] = (f16)acc[m][n][3];
        *(half4*)&Vtt[(((size_t)(b_ * 8 + h_)) * 64 + d_) * SS + s_] = ph;
      }
    }
  }
}

// ---------------- output GEMM: ctx2 halves summed, fp32 out ----------------
__global__ __launch_bounds__(256) void gemm_out(const f16* __restrict__ ctx2,
                                                const float* __restrict__ W,
                                                float* __restrict__ Out) {
  __shared__ f16 As[128][40];
  __shared__ f16 Bs[128][40];
  const int t = threadIdx.x;
  const int bm = blockIdx.x * 128;
  const int bn = blockIdx.y * 128;
  const int w = t >> 6, ln = t & 63;
  const int wr = w >> 1, wc = w & 1;
  const int lr = ln & 15, lg = ln >> 4;
  const int srow = t >> 1, scol = (t & 1) * 16;

  float4v acc[4][4] = {};

  for (int k0 = 0; k0 < 512; k0 += 32) {
    {
      const f16* ap = ctx2 + (size_t)(bm + srow) * 512 + k0 + scol;
      const f16* ap2 = ap + (size_t)MTOK * 512;
      half8 x0 = *(const half8*)(ap),  x1 = *(const half8*)(ap + 8);
      half8 y0 = *(const half8*)(ap2), y1 = *(const half8*)(ap2 + 8);
      *(half8*)&As[srow][scol]     = x0 + y0;
      *(half8*)&As[srow][scol + 8] = x1 + y1;
    }
    {
      const float* wp = W + (size_t)(bn + srow) * 512 + k0 + scol;
      float4v x0 = *(const float4v*)wp,       x1 = *(const float4v*)(wp + 4);
      float4v x2 = *(const float4v*)(wp + 8), x3 = *(const float4v*)(wp + 12);
      *(half8*)&Bs[srow][scol]     = cvt8(x0, x1);
      *(half8*)&Bs[srow][scol + 8] = cvt8(x2, x3);
    }
    __syncthreads();
    half8 af[4], bf[4];
    #pragma unroll
    for (int m = 0; m < 4; m++) af[m] = *(const half8*)&As[wr * 64 + m * 16 + lr][lg * 8];
    #pragma unroll
    for (int n = 0; n < 4; n++) bf[n] = *(const half8*)&Bs[wc * 64 + n * 16 + lr][lg * 8];
    #pragma unroll
    for (int m = 0; m < 4; m++)
      #pragma unroll
      for (int n = 0; n < 4; n++) acc[m][n] = mfma_k32(af[m], bf[n], acc[m][n]);
    __syncthreads();
  }

  #pragma unroll
  for (int m = 0; m < 4; m++) {
    int row = bm + wr * 64 + m * 16 + lg * 4;
    #pragma unroll
    for (int n = 0; n < 4; n++) {
      int col = bn + wc * 64 + n * 16 + lr;
      #pragma unroll
      for (int r = 0; r < 4; r++)
        Out[(size_t)(row + r) * 512 + col] = acc[m][n][r];
    }
  }
}

// ---------------- attention passes: wave = head, zero inner barriers ----------------
// Block = (b, kh-half, 16 q-rows); 512 thr = 8 waves; wave w handles head w
// over 16q x 1024k in 32 steps of 32k.  other+mask staged ONCE per block as
// masked f16 (33 KB LDS, +8 pad kills bank conflicts) -> read once from HBM.
// ONE barrier per block.  bid&7 = (b,kh) -> XCD: K+V working set 2 MB in L2.
// PASS 1: row-sums -> lsum2[kh] (no LDS reduce needed: wave spans full half).
// PASS 2: attn = E*invl (plain float4 stores, L2 merges to full lines) and
//   PV from REGISTERS: transposed-QK output (q=lane&15, k=(lane>>4)*4+r) is
//   exactly the 16x16x16 A-operand -> no P shuffle, no LDS, no barrier.
//   ctx2[kh] partial f16 (summed in gemm_out).
template<int PHASE>
__global__ __launch_bounds__(512, (PHASE == 1) ? 6 : 4) void attn_pass(
    const f16* __restrict__ Qp, const f16* __restrict__ Kpk,
    const f16* __restrict__ Vtt, const float* __restrict__ other,
    const unsigned char* __restrict__ mask8, const int* __restrict__ mask32,
    const unsigned int* __restrict__ flag, float* __restrict__ lsum2,
    float* __restrict__ attn_out, f16* __restrict__ ctx2) {
  __shared__ f16 othm[16][1032];   // masked, log2e-scaled, f16; +8 pad

  const int t = threadIdx.x;
  const int bid = blockIdx.x;
  const int b  = (bid >> 1) & 3;
  const int kh = bid & 1;
  const int qblk = (bid >> 3) * 16;
  const int w = t >> 6, ln = t & 63;
  const int lr = ln & 15, lg = ln >> 4;
  const bool use8 = (*flag) != 0;

  // ---- stage other+mask once (each thread: one q row, 32 k) ----
  {
    const int q = t >> 5, k0 = (t & 31) * 32;
    const size_t base = ((size_t)b * SS + qblk + q) * SS + kh * 1024 + k0;
    const float* op = other + base;
    if (use8) {
      const unsigned char* mp = mask8 + base;
      #pragma unroll
      for (int g = 0; g < 4; g++) {
        unsigned int mw0 = *(const unsigned int*)(mp + g * 8);
        unsigned int mw1 = *(const unsigned int*)(mp + g * 8 + 4);
        float4v o0 = *(const float4v*)(op + g * 8);
        float4v o1 = *(const float4v*)(op + g * 8 + 4);
        float4v r0, r1;
        #pragma unroll
        for (int r = 0; r < 4; r++) {
          r0[r] = ((mw0 >> (8 * r)) & 0xffu) ? MASKVAL : fmaf(o0[r], L2E, -EBIAS);
          r1[r] = ((mw1 >> (8 * r)) & 0xffu) ? MASKVAL : fmaf(o1[r], L2E, -EBIAS);
        }
        *(half8*)&othm[q][k0 + g * 8] = cvt8(r0, r1);
      }
    } else {
      const int* mp = mask32 + base;
      #pragma unroll
      for (int g = 0; g < 4; g++) {
        int4v m0 = *(const int4v*)(mp + g * 8);
        int4v m1 = *(const int4v*)(mp + g * 8 + 4);
        float4v o0 = *(const float4v*)(op + g * 8);
        float4v o1 = *(const float4v*)(op + g * 8 + 4);
        float4v r0, r1;
        #pragma unroll
        for (int r = 0; r < 4; r++) {
          r0[r] = m0[r] ? MASKVAL : fmaf(o0[r], L2E, -EBIAS);
          r1[r] = m1[r] ? MASKVAL : fmaf(o1[r], L2E, -EBIAS);
        }
        *(half8*)&othm[q][k0 + g * 8] = cvt8(r0, r1);
      }
    }
  }
  __syncthreads();  // the only barrier

  const int h = w, bh = b * 8 + h;
  // Q fragment (B-operand: col=q=lr)
  const f16* qp = Qp + ((size_t)b * SS + qblk + lr) * 512 + h * 64 + lg * 8;
  const half8 qf0 = *(const half8*)qp;
  const half8 qf1 = *(const half8*)(qp + 32);

  float invl = 0.f;
  if (PHASE == 2) {
    const size_t qi = (size_t)bh * SS + qblk + lr;
    invl = 1.0f / (lsum2[qi] + lsum2[(size_t)BHN * SS + qi]);
  }

  float rs = 0.f;
  float4v cacc[4] = {};

  const f16* kbase = Kpk + ((size_t)bh * SS + kh * 1024 + lr) * 64 + lg * 8;
  const f16* vbase = Vtt + ((size_t)bh * 64 + lr) * SS + kh * 1024;
  float* abase = attn_out + ((size_t)bh * SS + qblk + lr) * SS + kh * 1024;

  #pragma unroll 2
  for (int st = 0; st < 32; st++) {
    const int kl = st * 32;
    // K fragments (A-operand rows = k tokens)
    const f16* kp = kbase + (size_t)kl * 64;
    const half8 kf00 = *(const half8*)(kp);
    const half8 kf01 = *(const half8*)(kp + 32);
    const half8 kf10 = *(const half8*)(kp + 1024);        // +16 tokens
    const half8 kf11 = *(const half8*)(kp + 1024 + 32);
    float4v s0 = {}, s1 = {};
    s0 = mfma_k32(kf00, qf0, s0);
    s0 = mfma_k32(kf01, qf1, s0);
    s1 = mfma_k32(kf10, qf0, s1);
    s1 = mfma_k32(kf11, qf1, s1);
    #pragma unroll
    for (int n = 0; n < 2; n++) {
      const float4v sv = n ? s1 : s0;
      const int kln = kl + n * 16 + lg * 4;
      const half4 o4 = *(const half4*)&othm[lr][kln];
      float4v ev;
      #pragma unroll
      for (int r = 0; r < 4; r++)
        ev[r] = exp2f(fmaf(sv[r], SCALE_L2E, (float)o4[r]));
      if (PHASE == 1) {
        rs += (ev[0] + ev[1]) + (ev[2] + ev[3]);
      } else {
        float4v av = ev * invl;
        *(float4v*)(abase + kln) = av;                 // plain store: L2 merges
        half4 pa;
        pa[0] = (f16)av[0]; pa[1] = (f16)av[1];
        pa[2] = (f16)av[2]; pa[3] = (f16)av[3];
        // PV: pa IS the 16x16x16 A-operand (row=q=lr, k=lg*4+r)
        const f16* vp = vbase + kln;
        #pragma unroll
        for (int n2 = 0; n2 < 4; n2++) {
          half4 vf = *(const half4*)(vp + (size_t)n2 * 16 * SS);
          cacc[n2] = mfma_k16(pa, vf, cacc[n2]);
        }
      }
    }
  }

  if (PHASE == 1) {
    float v = rs;
    v += __shfl_xor(v, 16);
    v += __shfl_xor(v, 32);
    if (ln < 16)
      lsum2[(size_t)kh * BHN * SS + (size_t)bh * SS + qblk + lr] = v;
  } else {
    // ctx2: D layout of k16 PV: row=q=lg*4+r, col=dv=n2*16+lr (already normalized)
    #pragma unroll
    for (int n2 = 0; n2 < 4; n2++) {
      #pragma unroll
      for (int r = 0; r < 4; r++) {
        ctx2[(size_t)kh * MTOK * 512 +
             ((size_t)b * SS + qblk + lg * 4 + r) * 512 +
             h * 64 + n2 * 16 + lr] = (f16)cacc[n2][r];
      }
    }
  }
}

extern "C" void kernel_launch(void* const* d_in, const int* in_sizes, int n_in,
                              void* d_out, int out_size, void* d_ws, size_t ws_size,
                              hipStream_t stream) {
  const float* inQ   = (const float*)d_in[0];
  const float* inK   = (const float*)d_in[1];
  const float* inV   = (const float*)d_in[2];
  const void*  mask  = d_in[3];
  const float* other = (const float*)d_in[4];
  const float* WQ    = (const float*)d_in[5];
  const float* WK    = (const float*)d_in[6];
  const float* WV    = (const float*)d_in[7];
  const float* WF    = (const float*)d_in[8];

  char* ws = (char*)d_ws;
  size_t off = 0;
  unsigned int* flag = (unsigned int*)(ws + off); off += 256;
  f16* Qp    = (f16*)(ws + off); off += (size_t)MTOK * 512 * 2;
  f16* Kpk   = (f16*)(ws + off); off += (size_t)MTOK * 512 * 2;
  f16* Vtt   = (f16*)(ws + off); off += (size_t)MTOK * 512 * 2;
  float* lsum2 = (float*)(ws + off); off += (size_t)2 * BHN * SS * 4;
  f16* ctx2  = (f16*)(ws + off); off += (size_t)2 * MTOK * 512 * 2;
  if (ws_size < off) return;

  float* outp  = (float*)d_out;
  float* attnp = outp + (size_t)MTOK * DDIM;

  hipMemsetAsync(flag, 0, 256, stream);
  detect_mask_kernel<<<64, 256, 0, stream>>>((const unsigned int*)mask, flag);

  gemm_qkv<<<dim3(64, 4, 3), 256, 0, stream>>>(inQ, inK, inV, WQ, WK, WV,
                                               Qp, Kpk, Vtt);

  attn_pass<1><<<1024, 512, 0, stream>>>(
      Qp, Kpk, Vtt, other, (const unsigned char*)mask, (const int*)mask, flag,
      lsum2, attnp, ctx2);
  attn_pass<2><<<1024, 512, 0, stream>>>(
      Qp, Kpk, Vtt, other, (const unsigned char*)mask, (const int*)mask, flag,
      lsum2, attnp, ctx2);

  gemm_out<<<dim3(64, 4), 256, 0, stream>>>(ctx2, WF, outp);
}

// Round 9
// 377.548 us; speedup vs baseline: 1.8786x; 1.6575x over previous
//
#include <hip/hip_runtime.h>

#define BB 4
#define SS 2048
#define DDIM 512
#define HH 8
#define MTOK (BB*SS)   // 8192
#define BHN (BB*HH)    // 32

typedef _Float16 f16;
typedef __attribute__((ext_vector_type(8))) _Float16 half8;
typedef __attribute__((ext_vector_type(4))) _Float16 half4;
typedef __attribute__((ext_vector_type(4))) float float4v;
typedef __attribute__((ext_vector_type(4))) int int4v;

#define SCALE_L2E 0.180336880073616f   // 0.125 * log2(e)
#define L2E 1.44269504088896f
#define EBIAS 4.0f                     // cancels in softmax; f16 overflow headroom
#define MASKVAL -65504.0f              // f16 -max; exp2 -> 0

__device__ __forceinline__ float4v mfma_k32(half8 a, half8 b, float4v c) {
  return __builtin_amdgcn_mfma_f32_16x16x32_f16(a, b, c, 0, 0, 0);
}

__device__ __forceinline__ half8 cvt8(float4v a, float4v b) {
  half8 r;
  r[0] = (f16)a[0]; r[1] = (f16)a[1]; r[2] = (f16)a[2]; r[3] = (f16)a[3];
  r[4] = (f16)b[0]; r[5] = (f16)b[1]; r[6] = (f16)b[2]; r[7] = (f16)b[3];
  return r;
}

// ---------------- mask dtype detection ----------------
__global__ __launch_bounds__(256) void detect_mask_kernel(
    const unsigned int* __restrict__ m, unsigned int* __restrict__ flag) {
  unsigned int v = 0;
  const int base = blockIdx.x * 1024;
  for (int j = threadIdx.x; j < 1024; j += 256)
    if (m[base + j] > 1u) v = 1u;
  if (v) atomicOr(flag, 1u);
}

// ---------------- batched QKV projection ----------------
// z=0: Qp [tok][512] f16
// z=1: Kfrag[bh][tok>>4][dk>>5][(tok&15)+16*((dk>>3)&3)][dk&7]  (A-frag order)
// z=2: Vfrag[bh][tok>>5][dv>>4][(dv&15)+16*((tok>>2)&3)][((tok>>2)&4)+(tok&3)]
//      (B-frag order matching pa8 = [E(n=0), E(n=1)] k-slot packing)
__global__ __launch_bounds__(256) void gemm_qkv(
    const float* __restrict__ inQ, const float* __restrict__ inK,
    const float* __restrict__ inV, const float* __restrict__ WQ,
    const float* __restrict__ WK, const float* __restrict__ WV,
    f16* __restrict__ Qp, f16* __restrict__ Kfrag, f16* __restrict__ Vfrag) {
  __shared__ f16 As[128][40];
  __shared__ f16 Bs[128][40];
  const int z = blockIdx.z;
  const float* A = (z == 0) ? inQ : (z == 1) ? inK : inV;
  const float* W = (z == 0) ? WQ : (z == 1) ? WK : WV;
  const int t = threadIdx.x;
  const int bm = blockIdx.x * 128;
  const int bn = blockIdx.y * 128;
  const int w = t >> 6, ln = t & 63;
  const int wr = w >> 1, wc = w & 1;
  const int lr = ln & 15, lg = ln >> 4;
  const int srow = t >> 1, scol = (t & 1) * 16;

  float4v acc[4][4] = {};

  for (int k0 = 0; k0 < 512; k0 += 32) {
    {
      const float* ap = A + (size_t)(bm + srow) * 512 + k0 + scol;
      float4v x0 = *(const float4v*)ap,       x1 = *(const float4v*)(ap + 4);
      float4v x2 = *(const float4v*)(ap + 8), x3 = *(const float4v*)(ap + 12);
      *(half8*)&As[srow][scol]     = cvt8(x0, x1);
      *(half8*)&As[srow][scol + 8] = cvt8(x2, x3);
    }
    {
      const float* wp = W + (size_t)(bn + srow) * 512 + k0 + scol;
      float4v x0 = *(const float4v*)wp,       x1 = *(const float4v*)(wp + 4);
      float4v x2 = *(const float4v*)(wp + 8), x3 = *(const float4v*)(wp + 12);
      *(half8*)&Bs[srow][scol]     = cvt8(x0, x1);
      *(half8*)&Bs[srow][scol + 8] = cvt8(x2, x3);
    }
    __syncthreads();
    half8 af[4], bf[4];
    #pragma unroll
    for (int m = 0; m < 4; m++) af[m] = *(const half8*)&As[wr * 64 + m * 16 + lr][lg * 8];
    #pragma unroll
    for (int n = 0; n < 4; n++) bf[n] = *(const half8*)&Bs[wc * 64 + n * 16 + lr][lg * 8];
    #pragma unroll
    for (int m = 0; m < 4; m++)
      #pragma unroll
      for (int n = 0; n < 4; n++) acc[m][n] = mfma_k32(af[m], bf[n], acc[m][n]);
    __syncthreads();
  }

  #pragma unroll
  for (int m = 0; m < 4; m++) {
    int row = bm + wr * 64 + m * 16 + lg * 4;
    #pragma unroll
    for (int n = 0; n < 4; n++) {
      int col = bn + wc * 64 + n * 16 + lr;
      int b_ = row >> 11, s_ = row & 2047, h_ = col >> 6, d_ = col & 63;
      if (z == 0) {
        #pragma unroll
        for (int r = 0; r < 4; r++)
          Qp[(size_t)(row + r) * 512 + col] = (f16)acc[m][n][r];
      } else if (z == 1) {
        #pragma unroll
        for (int r = 0; r < 4; r++) {
          int tok = s_ + r;
          Kfrag[((((size_t)(b_ * 8 + h_)) * 128 + (tok >> 4)) * 2 + (d_ >> 5)) * 512 +
                ((tok & 15) + 16 * ((d_ >> 3) & 3)) * 8 + (d_ & 7)] =
              (f16)acc[m][n][r];
        }
      } else {
        half4 ph;
        ph[0] = (f16)acc[m][n][0]; ph[1] = (f16)acc[m][n][1];
        ph[2] = (f16)acc[m][n][2]; ph[3] = (f16)acc[m][n][3];
        *(half4*)&Vfrag[((((size_t)(b_ * 8 + h_)) * 64 + (s_ >> 5)) * 4 + (d_ >> 4)) * 512 +
                        ((d_ & 15) + 16 * ((s_ >> 2) & 3)) * 8 + ((s_ >> 2) & 4)] = ph;
      }
    }
  }
}

// ---------------- output GEMM: ctx2 halves summed, fp32 out ----------------
__global__ __launch_bounds__(256) void gemm_out(const f16* __restrict__ ctx2,
                                                const float* __restrict__ W,
                                                float* __restrict__ Out) {
  __shared__ f16 As[128][40];
  __shared__ f16 Bs[128][40];
  const int t = threadIdx.x;
  const int bm = blockIdx.x * 128;
  const int bn = blockIdx.y * 128;
  const int w = t >> 6, ln = t & 63;
  const int wr = w >> 1, wc = w & 1;
  const int lr = ln & 15, lg = ln >> 4;
  const int srow = t >> 1, scol = (t & 1) * 16;

  float4v acc[4][4] = {};

  for (int k0 = 0; k0 < 512; k0 += 32) {
    {
      const f16* ap = ctx2 + (size_t)(bm + srow) * 512 + k0 + scol;
      const f16* ap2 = ap + (size_t)MTOK * 512;
      half8 x0 = *(const half8*)(ap),  x1 = *(const half8*)(ap + 8);
      half8 y0 = *(const half8*)(ap2), y1 = *(const half8*)(ap2 + 8);
      *(half8*)&As[srow][scol]     = x0 + y0;
      *(half8*)&As[srow][scol + 8] = x1 + y1;
    }
    {
      const float* wp = W + (size_t)(bn + srow) * 512 + k0 + scol;
      float4v x0 = *(const float4v*)wp,       x1 = *(const float4v*)(wp + 4);
      float4v x2 = *(const float4v*)(wp + 8), x3 = *(const float4v*)(wp + 12);
      *(half8*)&Bs[srow][scol]     = cvt8(x0, x1);
      *(half8*)&Bs[srow][scol + 8] = cvt8(x2, x3);
    }
    __syncthreads();
    half8 af[4], bf[4];
    #pragma unroll
    for (int m = 0; m < 4; m++) af[m] = *(const half8*)&As[wr * 64 + m * 16 + lr][lg * 8];
    #pragma unroll
    for (int n = 0; n < 4; n++) bf[n] = *(const half8*)&Bs[wc * 64 + n * 16 + lr][lg * 8];
    #pragma unroll
    for (int m = 0; m < 4; m++)
      #pragma unroll
      for (int n = 0; n < 4; n++) acc[m][n] = mfma_k32(af[m], bf[n], acc[m][n]);
    __syncthreads();
  }

  #pragma unroll
  for (int m = 0; m < 4; m++) {
    int row = bm + wr * 64 + m * 16 + lg * 4;
    #pragma unroll
    for (int n = 0; n < 4; n++) {
      int col = bn + wc * 64 + n * 16 + lr;
      #pragma unroll
      for (int r = 0; r < 4; r++)
        Out[(size_t)(row + r) * 512 + col] = acc[m][n][r];
    }
  }
}

// ---------------- attention passes: wave = head, fragment-order K/V ----------------
// Block = (b, kh-half, 16 q-rows); 512 thr = 8 waves; wave w = head w over
// 16q x 1024k in 32 steps.  other+mask staged once per block (masked f16,
// 33 KB LDS) -> 1 barrier total.  K/V loads are FULLY COALESCED (1 KB/instr,
// fragment-order layouts) with explicit 2-deep register double-buffering.
// PASS 1: row sums.  PASS 2: attn = E*invl (plain float4 stores) + PV from
// registers via pa8 packing (16x16x32, k-slot order == Vfrag order).
#define LOADK(dst, st) {                                        \
    const f16* p_ = kfb + (size_t)(st) * 2048;                  \
    dst##0 = *(const half8*)(p_);                               \
    dst##1 = *(const half8*)(p_ + 512);                         \
    dst##2 = *(const half8*)(p_ + 1024);                        \
    dst##3 = *(const half8*)(p_ + 1536); }
#define LOADV(dst, st) {                                        \
    const f16* p_ = vfb + (size_t)(st) * 2048;                  \
    dst##0 = *(const half8*)(p_);                               \
    dst##1 = *(const half8*)(p_ + 512);                         \
    dst##2 = *(const half8*)(p_ + 1024);                        \
    dst##3 = *(const half8*)(p_ + 1536); }

template<int PHASE>
__global__ __launch_bounds__(512, (PHASE == 1) ? 6 : 4) void attn_pass(
    const f16* __restrict__ Qp, const f16* __restrict__ Kfrag,
    const f16* __restrict__ Vfrag, const float* __restrict__ other,
    const unsigned char* __restrict__ mask8, const int* __restrict__ mask32,
    const unsigned int* __restrict__ flag, float* __restrict__ lsum2,
    float* __restrict__ attn_out, f16* __restrict__ ctx2) {
  __shared__ f16 othm[16][1032];   // masked, log2e-scaled f16; +8 pad

  const int t = threadIdx.x;
  const int bid = blockIdx.x;
  const int b  = (bid >> 1) & 3;
  const int kh = bid & 1;
  const int qblk = (bid >> 3) * 16;
  const int w = t >> 6, ln = t & 63;
  const int lr = ln & 15, lg = ln >> 4;
  const bool use8 = (*flag) != 0;

  // ---- stage other+mask once ----
  {
    const int q = t >> 5, k0 = (t & 31) * 32;
    const size_t base = ((size_t)b * SS + qblk + q) * SS + kh * 1024 + k0;
    const float* op = other + base;
    if (use8) {
      const unsigned char* mp = mask8 + base;
      #pragma unroll
      for (int g = 0; g < 4; g++) {
        unsigned int mw0 = *(const unsigned int*)(mp + g * 8);
        unsigned int mw1 = *(const unsigned int*)(mp + g * 8 + 4);
        float4v o0 = *(const float4v*)(op + g * 8);
        float4v o1 = *(const float4v*)(op + g * 8 + 4);
        float4v r0, r1;
        #pragma unroll
        for (int r = 0; r < 4; r++) {
          r0[r] = ((mw0 >> (8 * r)) & 0xffu) ? MASKVAL : fmaf(o0[r], L2E, -EBIAS);
          r1[r] = ((mw1 >> (8 * r)) & 0xffu) ? MASKVAL : fmaf(o1[r], L2E, -EBIAS);
        }
        *(half8*)&othm[q][k0 + g * 8] = cvt8(r0, r1);
      }
    } else {
      const int* mp = mask32 + base;
      #pragma unroll
      for (int g = 0; g < 4; g++) {
        int4v m0 = *(const int4v*)(mp + g * 8);
        int4v m1 = *(const int4v*)(mp + g * 8 + 4);
        float4v o0 = *(const float4v*)(op + g * 8);
        float4v o1 = *(const float4v*)(op + g * 8 + 4);
        float4v r0, r1;
        #pragma unroll
        for (int r = 0; r < 4; r++) {
          r0[r] = m0[r] ? MASKVAL : fmaf(o0[r], L2E, -EBIAS);
          r1[r] = m1[r] ? MASKVAL : fmaf(o1[r], L2E, -EBIAS);
        }
        *(half8*)&othm[q][k0 + g * 8] = cvt8(r0, r1);
      }
    }
  }
  __syncthreads();  // the only barrier

  const int h = w, bh = b * 8 + h;
  const f16* qp = Qp + ((size_t)b * SS + qblk + lr) * 512 + h * 64 + lg * 8;
  const half8 qf0 = *(const half8*)qp;
  const half8 qf1 = *(const half8*)(qp + 32);

  float invl = 0.f;
  if (PHASE == 2) {
    const size_t qi = (size_t)bh * SS + qblk + lr;
    invl = 1.0f / (lsum2[qi] + lsum2[(size_t)BHN * SS + qi]);
  }

  float rs = 0.f;
  float4v cacc0 = {}, cacc1 = {}, cacc2 = {}, cacc3 = {};

  const f16* kfb = Kfrag + ((size_t)bh * 128 + kh * 64) * 2 * 512 + ln * 8;
  const f16* vfb = Vfrag + ((size_t)bh * 64 + kh * 32) * 4 * 512 + ln * 8;
  float* abase = attn_out + ((size_t)bh * SS + qblk + lr) * SS + kh * 1024;

  half8 kA0, kA1, kA2, kA3, kB0, kB1, kB2, kB3;
  half8 vA0, vA1, vA2, vA3, vB0, vB1, vB2, vB3;

  LOADK(kA, 0);
  if (PHASE == 2) LOADV(vA, 0);

  #define BODY(kf, vf, st) {                                              \
    const int stn = ((st) < 31) ? (st) + 1 : 31;                          \
    (void)stn;                                                            \
    float4v s0 = {}, s1 = {};                                             \
    s0 = mfma_k32(kf##0, qf0, s0);                                        \
    s0 = mfma_k32(kf##1, qf1, s0);                                        \
    s1 = mfma_k32(kf##2, qf0, s1);                                        \
    s1 = mfma_k32(kf##3, qf1, s1);                                        \
    const int kl = (st) * 32;                                             \
    const half4 o40 = *(const half4*)&othm[lr][kl + lg * 4];              \
    const half4 o41 = *(const half4*)&othm[lr][kl + 16 + lg * 4];         \
    float4v ev0, ev1;                                                     \
    _Pragma("unroll")                                                     \
    for (int r = 0; r < 4; r++) {                                         \
      ev0[r] = exp2f(fmaf(s0[r], SCALE_L2E, (float)o40[r]));              \
      ev1[r] = exp2f(fmaf(s1[r], SCALE_L2E, (float)o41[r]));              \
    }                                                                     \
    if (PHASE == 1) {                                                     \
      rs += (ev0[0] + ev0[1]) + (ev0[2] + ev0[3]) +                       \
            (ev1[0] + ev1[1]) + (ev1[2] + ev1[3]);                        \
    } else {                                                              \
      float4v av0 = ev0 * invl, av1 = ev1 * invl;                         \
      *(float4v*)(abase + kl + lg * 4) = av0;                             \
      *(float4v*)(abase + kl + 16 + lg * 4) = av1;                        \
      half8 pa8 = cvt8(av0, av1);                                         \
      cacc0 = mfma_k32(pa8, vf##0, cacc0);                                \
      cacc1 = mfma_k32(pa8, vf##1, cacc1);                                \
      cacc2 = mfma_k32(pa8, vf##2, cacc2);                                \
      cacc3 = mfma_k32(pa8, vf##3, cacc3);                                \
    }                                                                     \
  }

  for (int st2 = 0; st2 < 16; st2++) {
    const int se = st2 * 2;
    {
      const int stn = (se < 31) ? se + 1 : 31;
      LOADK(kB, stn);
      if (PHASE == 2) LOADV(vB, stn);
      BODY(kA, vA, se);
    }
    {
      const int so = se + 1;
      const int stn = (so < 31) ? so + 1 : 31;
      LOADK(kA, stn);
      if (PHASE == 2) LOADV(vA, stn);
      BODY(kB, vB, so);
    }
  }
  #undef BODY

  if (PHASE == 1) {
    float v = rs;
    v += __shfl_xor(v, 16);
    v += __shfl_xor(v, 32);
    if (ln < 16)
      lsum2[(size_t)kh * BHN * SS + (size_t)bh * SS + qblk + lr] = v;
  } else {
    // D layout: row=q=lg*4+r, col=dv=n2*16+lr (already normalized)
    #pragma unroll
    for (int r = 0; r < 4; r++) {
      const size_t crow = (size_t)kh * MTOK * 512 +
                          ((size_t)b * SS + qblk + lg * 4 + r) * 512 + h * 64;
      ctx2[crow + 0 * 16 + lr] = (f16)cacc0[r];
      ctx2[crow + 1 * 16 + lr] = (f16)cacc1[r];
      ctx2[crow + 2 * 16 + lr] = (f16)cacc2[r];
      ctx2[crow + 3 * 16 + lr] = (f16)cacc3[r];
    }
  }
}

extern "C" void kernel_launch(void* const* d_in, const int* in_sizes, int n_in,
                              void* d_out, int out_size, void* d_ws, size_t ws_size,
                              hipStream_t stream) {
  const float* inQ   = (const float*)d_in[0];
  const float* inK   = (const float*)d_in[1];
  const float* inV   = (const float*)d_in[2];
  const void*  mask  = d_in[3];
  const float* other = (const float*)d_in[4];
  const float* WQ    = (const float*)d_in[5];
  const float* WK    = (const float*)d_in[6];
  const float* WV    = (const float*)d_in[7];
  const float* WF    = (const float*)d_in[8];

  char* ws = (char*)d_ws;
  size_t off = 0;
  unsigned int* flag = (unsigned int*)(ws + off); off += 256;
  f16* Qp    = (f16*)(ws + off); off += (size_t)MTOK * 512 * 2;
  f16* Kfrag = (f16*)(ws + off); off += (size_t)MTOK * 512 * 2;
  f16* Vfrag = (f16*)(ws + off); off += (size_t)MTOK * 512 * 2;
  float* lsum2 = (float*)(ws + off); off += (size_t)2 * BHN * SS * 4;
  f16* ctx2  = (f16*)(ws + off); off += (size_t)2 * MTOK * 512 * 2;
  if (ws_size < off) return;

  float* outp  = (float*)d_out;
  float* attnp = outp + (size_t)MTOK * DDIM;

  hipMemsetAsync(flag, 0, 256, stream);
  detect_mask_kernel<<<64, 256, 0, stream>>>((const unsigned int*)mask, flag);

  gemm_qkv<<<dim3(64, 4, 3), 256, 0, stream>>>(inQ, inK, inV, WQ, WK, WV,
                                               Qp, Kfrag, Vfrag);

  attn_pass<1><<<1024, 512, 0, stream>>>(
      Qp, Kfrag, Vfrag, other, (const unsigned char*)mask, (const int*)mask,
      flag, lsum2, attnp, ctx2);
  attn_pass<2><<<1024, 512, 0, stream>>>(
      Qp, Kfrag, Vfrag, other, (const unsigned char*)mask, (const int*)mask,
      flag, lsum2, attnp, ctx2);

  gemm_out<<<dim3(64, 4), 256, 0, stream>>>(ctx2, WF, outp);
}

// Round 10
// 363.984 us; speedup vs baseline: 1.9486x; 1.0373x over previous
//
#include <hip/hip_runtime.h>

#define BB 4
#define SS 2048
#define DDIM 512
#define HH 8
#define MTOK (BB*SS)   // 8192
#define BHN (BB*HH)    // 32

typedef _Float16 f16;
typedef __attribute__((ext_vector_type(8))) _Float16 half8;
typedef __attribute__((ext_vector_type(4))) _Float16 half4;
typedef __attribute__((ext_vector_type(4))) float float4v;
typedef __attribute__((ext_vector_type(4))) int int4v;

#define SCALE_L2E 0.180336880073616f   // 0.125 * log2(e)
#define L2E 1.44269504088896f
#define EBIAS 4.0f                     // cancels in softmax; f16 overflow headroom
#define MASKVAL -65504.0f              // f16 -max; exp2 -> 0

__device__ __forceinline__ float4v mfma_k32(half8 a, half8 b, float4v c) {
  return __builtin_amdgcn_mfma_f32_16x16x32_f16(a, b, c, 0, 0, 0);
}

__device__ __forceinline__ half8 cvt8(float4v a, float4v b) {
  half8 r;
  r[0] = (f16)a[0]; r[1] = (f16)a[1]; r[2] = (f16)a[2]; r[3] = (f16)a[3];
  r[4] = (f16)b[0]; r[5] = (f16)b[1]; r[6] = (f16)b[2]; r[7] = (f16)b[3];
  return r;
}

// ---------------- mask dtype detection ----------------
__global__ __launch_bounds__(256) void detect_mask_kernel(
    const unsigned int* __restrict__ m, unsigned int* __restrict__ flag) {
  unsigned int v = 0;
  const int base = blockIdx.x * 1024;
  for (int j = threadIdx.x; j < 1024; j += 256)
    if (m[base + j] > 1u) v = 1u;
  if (v) atomicOr(flag, 1u);
}

// ---------------- batched QKV projection ----------------
// z=0: Qp [tok][512] f16
// z=1: Kfrag[bh][tok>>4][dk>>5][(tok&15)+16*((dk>>3)&3)][dk&7]  (A-frag order)
// z=2: Vfrag[bh][tok>>5][dv>>4][(dv&15)+16*((tok>>2)&3)][((tok>>2)&4)+(tok&3)]
__global__ __launch_bounds__(256) void gemm_qkv(
    const float* __restrict__ inQ, const float* __restrict__ inK,
    const float* __restrict__ inV, const float* __restrict__ WQ,
    const float* __restrict__ WK, const float* __restrict__ WV,
    f16* __restrict__ Qp, f16* __restrict__ Kfrag, f16* __restrict__ Vfrag) {
  __shared__ f16 As[128][40];
  __shared__ f16 Bs[128][40];
  const int z = blockIdx.z;
  const float* A = (z == 0) ? inQ : (z == 1) ? inK : inV;
  const float* W = (z == 0) ? WQ : (z == 1) ? WK : WV;
  const int t = threadIdx.x;
  const int bm = blockIdx.x * 128;
  const int bn = blockIdx.y * 128;
  const int w = t >> 6, ln = t & 63;
  const int wr = w >> 1, wc = w & 1;
  const int lr = ln & 15, lg = ln >> 4;
  const int srow = t >> 1, scol = (t & 1) * 16;

  float4v acc[4][4] = {};

  for (int k0 = 0; k0 < 512; k0 += 32) {
    {
      const float* ap = A + (size_t)(bm + srow) * 512 + k0 + scol;
      float4v x0 = *(const float4v*)ap,       x1 = *(const float4v*)(ap + 4);
      float4v x2 = *(const float4v*)(ap + 8), x3 = *(const float4v*)(ap + 12);
      *(half8*)&As[srow][scol]     = cvt8(x0, x1);
      *(half8*)&As[srow][scol + 8] = cvt8(x2, x3);
    }
    {
      const float* wp = W + (size_t)(bn + srow) * 512 + k0 + scol;
      float4v x0 = *(const float4v*)wp,       x1 = *(const float4v*)(wp + 4);
      float4v x2 = *(const float4v*)(wp + 8), x3 = *(const float4v*)(wp + 12);
      *(half8*)&Bs[srow][scol]     = cvt8(x0, x1);
      *(half8*)&Bs[srow][scol + 8] = cvt8(x2, x3);
    }
    __syncthreads();
    half8 af[4], bf[4];
    #pragma unroll
    for (int m = 0; m < 4; m++) af[m] = *(const half8*)&As[wr * 64 + m * 16 + lr][lg * 8];
    #pragma unroll
    for (int n = 0; n < 4; n++) bf[n] = *(const half8*)&Bs[wc * 64 + n * 16 + lr][lg * 8];
    #pragma unroll
    for (int m = 0; m < 4; m++)
      #pragma unroll
      for (int n = 0; n < 4; n++) acc[m][n] = mfma_k32(af[m], bf[n], acc[m][n]);
    __syncthreads();
  }

  #pragma unroll
  for (int m = 0; m < 4; m++) {
    int row = bm + wr * 64 + m * 16 + lg * 4;
    #pragma unroll
    for (int n = 0; n < 4; n++) {
      int col = bn + wc * 64 + n * 16 + lr;
      int b_ = row >> 11, s_ = row & 2047, h_ = col >> 6, d_ = col & 63;
      if (z == 0) {
        #pragma unroll
        for (int r = 0; r < 4; r++)
          Qp[(size_t)(row + r) * 512 + col] = (f16)acc[m][n][r];
      } else if (z == 1) {
        #pragma unroll
        for (int r = 0; r < 4; r++) {
          int tok = s_ + r;
          Kfrag[((((size_t)(b_ * 8 + h_)) * 128 + (tok >> 4)) * 2 + (d_ >> 5)) * 512 +
                ((tok & 15) + 16 * ((d_ >> 3) & 3)) * 8 + (d_ & 7)] =
              (f16)acc[m][n][r];
        }
      } else {
        half4 ph;
        ph[0] = (f16)acc[m][n][0]; ph[1] = (f16)acc[m][n][1];
        ph[2] = (f16)acc[m][n][2]; ph[3] = (f16)acc[m][n][3];
        *(half4*)&Vfrag[((((size_t)(b_ * 8 + h_)) * 64 + (s_ >> 5)) * 4 + (d_ >> 4)) * 512 +
                        ((d_ & 15) + 16 * ((s_ >> 2) & 3)) * 8 + ((s_ >> 2) & 4)] = ph;
      }
    }
  }
}

// ---------------- output GEMM: ctx (f16) x W_fc^T -> fp32 ----------------
__global__ __launch_bounds__(256) void gemm_out(const f16* __restrict__ ctx,
                                                const float* __restrict__ W,
                                                float* __restrict__ Out) {
  __shared__ f16 As[128][40];
  __shared__ f16 Bs[128][40];
  const int t = threadIdx.x;
  const int bm = blockIdx.x * 128;
  const int bn = blockIdx.y * 128;
  const int w = t >> 6, ln = t & 63;
  const int wr = w >> 1, wc = w & 1;
  const int lr = ln & 15, lg = ln >> 4;
  const int srow = t >> 1, scol = (t & 1) * 16;

  float4v acc[4][4] = {};

  for (int k0 = 0; k0 < 512; k0 += 32) {
    {
      const f16* ap = ctx + (size_t)(bm + srow) * 512 + k0 + scol;
      *(half8*)&As[srow][scol]     = *(const half8*)(ap);
      *(half8*)&As[srow][scol + 8] = *(const half8*)(ap + 8);
    }
    {
      const float* wp = W + (size_t)(bn + srow) * 512 + k0 + scol;
      float4v x0 = *(const float4v*)wp,       x1 = *(const float4v*)(wp + 4);
      float4v x2 = *(const float4v*)(wp + 8), x3 = *(const float4v*)(wp + 12);
      *(half8*)&Bs[srow][scol]     = cvt8(x0, x1);
      *(half8*)&Bs[srow][scol + 8] = cvt8(x2, x3);
    }
    __syncthreads();
    half8 af[4], bf[4];
    #pragma unroll
    for (int m = 0; m < 4; m++) af[m] = *(const half8*)&As[wr * 64 + m * 16 + lr][lg * 8];
    #pragma unroll
    for (int n = 0; n < 4; n++) bf[n] = *(const half8*)&Bs[wc * 64 + n * 16 + lr][lg * 8];
    #pragma unroll
    for (int m = 0; m < 4; m++)
      #pragma unroll
      for (int n = 0; n < 4; n++) acc[m][n] = mfma_k32(af[m], bf[n], acc[m][n]);
    __syncthreads();
  }

  #pragma unroll
  for (int m = 0; m < 4; m++) {
    int row = bm + wr * 64 + m * 16 + lg * 4;
    #pragma unroll
    for (int n = 0; n < 4; n++) {
      int col = bn + wc * 64 + n * 16 + lr;
      #pragma unroll
      for (int r = 0; r < 4; r++)
        Out[(size_t)(row + r) * 512 + col] = acc[m][n][r];
    }
  }
}

// ---------------- single fused attention: wave = head, full k-range ----------------
// Block = (b, 16 q-rows); 512 thr = 8 waves; wave w = head w over 16q x 2048k.
// other+mask staged ONCE per block into 66 KB LDS f16 -> read once from HBM
// for BOTH passes.  1 barrier total.  b = bid&3 -> XCD: K+V slice ~4 MB ~ L2.
// Pass A: QK^T+exp rowsum over all 2048 k (K coalesced fragment-order,
//   2-deep register pipeline); row sum reduced IN-WAVE (2 shfl_xor) -> invl.
// Pass B: recompute E from LDS othm, attn = E*invl (plain float4 stores),
//   PV from registers (pa8 packing, 16x16x32).  ctx written whole (no split).
#define LOADK(dst, st) {                                        \
    const f16* p_ = kfb + (size_t)(st) * 2048;                  \
    dst##0 = *(const half8*)(p_);                               \
    dst##1 = *(const half8*)(p_ + 512);                         \
    dst##2 = *(const half8*)(p_ + 1024);                        \
    dst##3 = *(const half8*)(p_ + 1536); }
#define LOADV(dst, st) {                                        \
    const f16* p_ = vfb + (size_t)(st) * 2048;                  \
    dst##0 = *(const half8*)(p_);                               \
    dst##1 = *(const half8*)(p_ + 512);                         \
    dst##2 = *(const half8*)(p_ + 1024);                        \
    dst##3 = *(const half8*)(p_ + 1536); }

__global__ __launch_bounds__(512, 2) void attn_fused(
    const f16* __restrict__ Qp, const f16* __restrict__ Kfrag,
    const f16* __restrict__ Vfrag, const float* __restrict__ other,
    const unsigned char* __restrict__ mask8, const int* __restrict__ mask32,
    const unsigned int* __restrict__ flag, float* __restrict__ attn_out,
    f16* __restrict__ ctx) {
  __shared__ f16 othm[16][2056];   // masked, log2e-scaled f16; +8 pad

  const int t = threadIdx.x;
  const int bid = blockIdx.x;
  const int b = bid & 3;
  const int qblk = (bid >> 2) * 16;
  const int w = t >> 6, ln = t & 63;
  const int lr = ln & 15, lg = ln >> 4;
  const bool use8 = (*flag) != 0;

  // ---- stage other+mask once: thread -> (q = t>>5, 64 k at (t&31)*64) ----
  {
    const int q = t >> 5, k0 = (t & 31) * 64;
    const size_t base = ((size_t)b * SS + qblk + q) * SS + k0;
    const float* op = other + base;
    if (use8) {
      const unsigned char* mp = mask8 + base;
      #pragma unroll
      for (int g = 0; g < 8; g++) {
        unsigned int mw0 = *(const unsigned int*)(mp + g * 8);
        unsigned int mw1 = *(const unsigned int*)(mp + g * 8 + 4);
        float4v o0 = *(const float4v*)(op + g * 8);
        float4v o1 = *(const float4v*)(op + g * 8 + 4);
        float4v r0, r1;
        #pragma unroll
        for (int r = 0; r < 4; r++) {
          r0[r] = ((mw0 >> (8 * r)) & 0xffu) ? MASKVAL : fmaf(o0[r], L2E, -EBIAS);
          r1[r] = ((mw1 >> (8 * r)) & 0xffu) ? MASKVAL : fmaf(o1[r], L2E, -EBIAS);
        }
        *(half8*)&othm[q][k0 + g * 8] = cvt8(r0, r1);
      }
    } else {
      const int* mp = mask32 + base;
      #pragma unroll
      for (int g = 0; g < 8; g++) {
        int4v m0 = *(const int4v*)(mp + g * 8);
        int4v m1 = *(const int4v*)(mp + g * 8 + 4);
        float4v o0 = *(const float4v*)(op + g * 8);
        float4v o1 = *(const float4v*)(op + g * 8 + 4);
        float4v r0, r1;
        #pragma unroll
        for (int r = 0; r < 4; r++) {
          r0[r] = m0[r] ? MASKVAL : fmaf(o0[r], L2E, -EBIAS);
          r1[r] = m1[r] ? MASKVAL : fmaf(o1[r], L2E, -EBIAS);
        }
        *(half8*)&othm[q][k0 + g * 8] = cvt8(r0, r1);
      }
    }
  }
  __syncthreads();  // the only barrier

  const int h = w, bh = b * 8 + h;
  const f16* qp = Qp + ((size_t)b * SS + qblk + lr) * 512 + h * 64 + lg * 8;
  const half8 qf0 = *(const half8*)qp;
  const half8 qf1 = *(const half8*)(qp + 32);

  const f16* kfb = Kfrag + (size_t)bh * 128 * 2 * 512 + ln * 8;
  const f16* vfb = Vfrag + (size_t)bh * 64 * 4 * 512 + ln * 8;
  float* abase = attn_out + ((size_t)bh * SS + qblk + lr) * SS;

  half8 kA0, kA1, kA2, kA3, kB0, kB1, kB2, kB3;
  half8 vA0, vA1, vA2, vA3, vB0, vB1, vB2, vB3;

  // ================= pass A: row sums =================
  float rs = 0.f;
  LOADK(kA, 0);

  #define BODYA(kf, st) {                                                 \
    float4v s0 = {}, s1 = {};                                             \
    s0 = mfma_k32(kf##0, qf0, s0);                                        \
    s0 = mfma_k32(kf##1, qf1, s0);                                        \
    s1 = mfma_k32(kf##2, qf0, s1);                                        \
    s1 = mfma_k32(kf##3, qf1, s1);                                        \
    const int kl = (st) * 32;                                             \
    const half4 o40 = *(const half4*)&othm[lr][kl + lg * 4];              \
    const half4 o41 = *(const half4*)&othm[lr][kl + 16 + lg * 4];         \
    float4v ev0, ev1;                                                     \
    _Pragma("unroll")                                                     \
    for (int r = 0; r < 4; r++) {                                         \
      ev0[r] = exp2f(fmaf(s0[r], SCALE_L2E, (float)o40[r]));              \
      ev1[r] = exp2f(fmaf(s1[r], SCALE_L2E, (float)o41[r]));              \
    }                                                                     \
    rs += (ev0[0] + ev0[1]) + (ev0[2] + ev0[3]) +                         \
          (ev1[0] + ev1[1]) + (ev1[2] + ev1[3]);                          \
  }

  for (int st2 = 0; st2 < 32; st2++) {
    const int se = st2 * 2;
    {
      LOADK(kB, se + 1);
      BODYA(kA, se);
    }
    {
      const int so = se + 1;
      const int stn = (so < 63) ? so + 1 : 63;
      LOADK(kA, stn);
      BODYA(kB, so);
    }
  }
  #undef BODYA

  // in-wave row-sum reduce (q = lr; partials across lg groups)
  rs += __shfl_xor(rs, 16);
  rs += __shfl_xor(rs, 32);
  const float invl = 1.0f / rs;

  // ================= pass B: normalize + attn store + PV =================
  float4v cacc0 = {}, cacc1 = {}, cacc2 = {}, cacc3 = {};
  LOADK(kA, 0);
  LOADV(vA, 0);

  #define BODYB(kf, vf, st) {                                             \
    float4v s0 = {}, s1 = {};                                             \
    s0 = mfma_k32(kf##0, qf0, s0);                                        \
    s0 = mfma_k32(kf##1, qf1, s0);                                        \
    s1 = mfma_k32(kf##2, qf0, s1);                                        \
    s1 = mfma_k32(kf##3, qf1, s1);                                        \
    const int kl = (st) * 32;                                             \
    const half4 o40 = *(const half4*)&othm[lr][kl + lg * 4];              \
    const half4 o41 = *(const half4*)&othm[lr][kl + 16 + lg * 4];         \
    float4v ev0, ev1;                                                     \
    _Pragma("unroll")                                                     \
    for (int r = 0; r < 4; r++) {                                         \
      ev0[r] = exp2f(fmaf(s0[r], SCALE_L2E, (float)o40[r]));              \
      ev1[r] = exp2f(fmaf(s1[r], SCALE_L2E, (float)o41[r]));              \
    }                                                                     \
    float4v av0 = ev0 * invl, av1 = ev1 * invl;                           \
    *(float4v*)(abase + kl + lg * 4) = av0;                               \
    *(float4v*)(abase + kl + 16 + lg * 4) = av1;                          \
    half8 pa8 = cvt8(av0, av1);                                           \
    cacc0 = mfma_k32(pa8, vf##0, cacc0);                                  \
    cacc1 = mfma_k32(pa8, vf##1, cacc1);                                  \
    cacc2 = mfma_k32(pa8, vf##2, cacc2);                                  \
    cacc3 = mfma_k32(pa8, vf##3, cacc3);                                  \
  }

  for (int st2 = 0; st2 < 32; st2++) {
    const int se = st2 * 2;
    {
      LOADK(kB, se + 1);
      LOADV(vB, se + 1);
      BODYB(kA, vA, se);
    }
    {
      const int so = se + 1;
      const int stn = (so < 63) ? so + 1 : 63;
      LOADK(kA, stn);
      LOADV(vA, stn);
      BODYB(kB, vB, so);
    }
  }
  #undef BODYB

  // ctx: D layout row=q=lg*4+r, col=dv=n2*16+lr (already normalized)
  #pragma unroll
  for (int r = 0; r < 4; r++) {
    const size_t crow = ((size_t)b * SS + qblk + lg * 4 + r) * 512 + h * 64;
    ctx[crow + 0 * 16 + lr] = (f16)cacc0[r];
    ctx[crow + 1 * 16 + lr] = (f16)cacc1[r];
    ctx[crow + 2 * 16 + lr] = (f16)cacc2[r];
    ctx[crow + 3 * 16 + lr] = (f16)cacc3[r];
  }
}

extern "C" void kernel_launch(void* const* d_in, const int* in_sizes, int n_in,
                              void* d_out, int out_size, void* d_ws, size_t ws_size,
                              hipStream_t stream) {
  const float* inQ   = (const float*)d_in[0];
  const float* inK   = (const float*)d_in[1];
  const float* inV   = (const float*)d_in[2];
  const void*  mask  = d_in[3];
  const float* other = (const float*)d_in[4];
  const float* WQ    = (const float*)d_in[5];
  const float* WK    = (const float*)d_in[6];
  const float* WV    = (const float*)d_in[7];
  const float* WF    = (const float*)d_in[8];

  char* ws = (char*)d_ws;
  size_t off = 0;
  unsigned int* flag = (unsigned int*)(ws + off); off += 256;
  f16* Qp    = (f16*)(ws + off); off += (size_t)MTOK * 512 * 2;
  f16* Kfrag = (f16*)(ws + off); off += (size_t)MTOK * 512 * 2;
  f16* Vfrag = (f16*)(ws + off); off += (size_t)MTOK * 512 * 2;
  f16* ctx   = (f16*)(ws + off); off += (size_t)MTOK * 512 * 2;
  if (ws_size < off) return;

  float* outp  = (float*)d_out;
  float* attnp = outp + (size_t)MTOK * DDIM;

  hipMemsetAsync(flag, 0, 256, stream);
  detect_mask_kernel<<<64, 256, 0, stream>>>((const unsigned int*)mask, flag);

  gemm_qkv<<<dim3(64, 4, 3), 256, 0, stream>>>(inQ, inK, inV, WQ, WK, WV,
                                               Qp, Kfrag, Vfrag);

  attn_fused<<<512, 512, 0, stream>>>(
      Qp, Kfrag, Vfrag, other, (const unsigned char*)mask, (const int*)mask,
      flag, attnp, ctx);

  gemm_out<<<dim3(64, 4), 256, 0, stream>>>(ctx, WF, outp);
}

// Round 11
// 334.074 us; speedup vs baseline: 2.1230x; 1.0895x over previous
//
#include <hip/hip_runtime.h>

#define BB 4
#define SS 2048
#define DDIM 512
#define HH 8
#define MTOK (BB*SS)   // 8192
#define BHN (BB*HH)    // 32

typedef _Float16 f16;
typedef __attribute__((ext_vector_type(8))) _Float16 half8;
typedef __attribute__((ext_vector_type(4))) _Float16 half4;
typedef __attribute__((ext_vector_type(4))) float float4v;
typedef __attribute__((ext_vector_type(4))) int int4v;

#define SCALE_L2E 0.180336880073616f   // 0.125 * log2(e)
#define L2E 1.44269504088896f
#define EBIAS 4.0f                     // cancels in softmax; f16 overflow headroom
#define MASKVAL -65504.0f              // f16 -max; exp2 -> 0

__device__ __forceinline__ float4v mfma_k32(half8 a, half8 b, float4v c) {
  return __builtin_amdgcn_mfma_f32_16x16x32_f16(a, b, c, 0, 0, 0);
}

__device__ __forceinline__ half8 cvt8(float4v a, float4v b) {
  half8 r;
  r[0] = (f16)a[0]; r[1] = (f16)a[1]; r[2] = (f16)a[2]; r[3] = (f16)a[3];
  r[4] = (f16)b[0]; r[5] = (f16)b[1]; r[6] = (f16)b[2]; r[7] = (f16)b[3];
  return r;
}

// ---------------- mask dtype detection ----------------
__global__ __launch_bounds__(256) void detect_mask_kernel(
    const unsigned int* __restrict__ m, unsigned int* __restrict__ flag) {
  unsigned int v = 0;
  const int base = blockIdx.x * 1024;
  for (int j = threadIdx.x; j < 1024; j += 256)
    if (m[base + j] > 1u) v = 1u;
  if (v) atomicOr(flag, 1u);
}

// ---------------- batched QKV projection ----------------
// z=0: Qp [tok][512] f16
// z=1: Kfrag[bh][tok>>4][dk>>5][(tok&15)+16*((dk>>3)&3)][dk&7]  (A-frag order)
// z=2: Vfrag[bh][tok>>5][dv>>4][(dv&15)+16*((tok>>2)&3)][((tok>>2)&4)+(tok&3)]
__global__ __launch_bounds__(256) void gemm_qkv(
    const float* __restrict__ inQ, const float* __restrict__ inK,
    const float* __restrict__ inV, const float* __restrict__ WQ,
    const float* __restrict__ WK, const float* __restrict__ WV,
    f16* __restrict__ Qp, f16* __restrict__ Kfrag, f16* __restrict__ Vfrag) {
  __shared__ f16 As[128][40];
  __shared__ f16 Bs[128][40];
  const int z = blockIdx.z;
  const float* A = (z == 0) ? inQ : (z == 1) ? inK : inV;
  const float* W = (z == 0) ? WQ : (z == 1) ? WK : WV;
  const int t = threadIdx.x;
  const int bm = blockIdx.x * 128;
  const int bn = blockIdx.y * 128;
  const int w = t >> 6, ln = t & 63;
  const int wr = w >> 1, wc = w & 1;
  const int lr = ln & 15, lg = ln >> 4;
  const int srow = t >> 1, scol = (t & 1) * 16;

  float4v acc[4][4] = {};

  for (int k0 = 0; k0 < 512; k0 += 32) {
    {
      const float* ap = A + (size_t)(bm + srow) * 512 + k0 + scol;
      float4v x0 = *(const float4v*)ap,       x1 = *(const float4v*)(ap + 4);
      float4v x2 = *(const float4v*)(ap + 8), x3 = *(const float4v*)(ap + 12);
      *(half8*)&As[srow][scol]     = cvt8(x0, x1);
      *(half8*)&As[srow][scol + 8] = cvt8(x2, x3);
    }
    {
      const float* wp = W + (size_t)(bn + srow) * 512 + k0 + scol;
      float4v x0 = *(const float4v*)wp,       x1 = *(const float4v*)(wp + 4);
      float4v x2 = *(const float4v*)(wp + 8), x3 = *(const float4v*)(wp + 12);
      *(half8*)&Bs[srow][scol]     = cvt8(x0, x1);
      *(half8*)&Bs[srow][scol + 8] = cvt8(x2, x3);
    }
    __syncthreads();
    half8 af[4], bf[4];
    #pragma unroll
    for (int m = 0; m < 4; m++) af[m] = *(const half8*)&As[wr * 64 + m * 16 + lr][lg * 8];
    #pragma unroll
    for (int n = 0; n < 4; n++) bf[n] = *(const half8*)&Bs[wc * 64 + n * 16 + lr][lg * 8];
    #pragma unroll
    for (int m = 0; m < 4; m++)
      #pragma unroll
      for (int n = 0; n < 4; n++) acc[m][n] = mfma_k32(af[m], bf[n], acc[m][n]);
    __syncthreads();
  }

  #pragma unroll
  for (int m = 0; m < 4; m++) {
    int row = bm + wr * 64 + m * 16 + lg * 4;
    #pragma unroll
    for (int n = 0; n < 4; n++) {
      int col = bn + wc * 64 + n * 16 + lr;
      int b_ = row >> 11, s_ = row & 2047, h_ = col >> 6, d_ = col & 63;
      if (z == 0) {
        #pragma unroll
        for (int r = 0; r < 4; r++)
          Qp[(size_t)(row + r) * 512 + col] = (f16)acc[m][n][r];
      } else if (z == 1) {
        #pragma unroll
        for (int r = 0; r < 4; r++) {
          int tok = s_ + r;
          Kfrag[((((size_t)(b_ * 8 + h_)) * 128 + (tok >> 4)) * 2 + (d_ >> 5)) * 512 +
                ((tok & 15) + 16 * ((d_ >> 3) & 3)) * 8 + (d_ & 7)] =
              (f16)acc[m][n][r];
        }
      } else {
        half4 ph;
        ph[0] = (f16)acc[m][n][0]; ph[1] = (f16)acc[m][n][1];
        ph[2] = (f16)acc[m][n][2]; ph[3] = (f16)acc[m][n][3];
        *(half4*)&Vfrag[((((size_t)(b_ * 8 + h_)) * 64 + (s_ >> 5)) * 4 + (d_ >> 4)) * 512 +
                        ((d_ & 15) + 16 * ((s_ >> 2) & 3)) * 8 + ((s_ >> 2) & 4)] = ph;
      }
    }
  }
}

// ---------------- output GEMM: ctx (f16) x W_fc^T -> fp32 ----------------
__global__ __launch_bounds__(256) void gemm_out(const f16* __restrict__ ctx,
                                                const float* __restrict__ W,
                                                float* __restrict__ Out) {
  __shared__ f16 As[128][40];
  __shared__ f16 Bs[128][40];
  const int t = threadIdx.x;
  const int bm = blockIdx.x * 128;
  const int bn = blockIdx.y * 128;
  const int w = t >> 6, ln = t & 63;
  const int wr = w >> 1, wc = w & 1;
  const int lr = ln & 15, lg = ln >> 4;
  const int srow = t >> 1, scol = (t & 1) * 16;

  float4v acc[4][4] = {};

  for (int k0 = 0; k0 < 512; k0 += 32) {
    {
      const f16* ap = ctx + (size_t)(bm + srow) * 512 + k0 + scol;
      *(half8*)&As[srow][scol]     = *(const half8*)(ap);
      *(half8*)&As[srow][scol + 8] = *(const half8*)(ap + 8);
    }
    {
      const float* wp = W + (size_t)(bn + srow) * 512 + k0 + scol;
      float4v x0 = *(const float4v*)wp,       x1 = *(const float4v*)(wp + 4);
      float4v x2 = *(const float4v*)(wp + 8), x3 = *(const float4v*)(wp + 12);
      *(half8*)&Bs[srow][scol]     = cvt8(x0, x1);
      *(half8*)&Bs[srow][scol + 8] = cvt8(x2, x3);
    }
    __syncthreads();
    half8 af[4], bf[4];
    #pragma unroll
    for (int m = 0; m < 4; m++) af[m] = *(const half8*)&As[wr * 64 + m * 16 + lr][lg * 8];
    #pragma unroll
    for (int n = 0; n < 4; n++) bf[n] = *(const half8*)&Bs[wc * 64 + n * 16 + lr][lg * 8];
    #pragma unroll
    for (int m = 0; m < 4; m++)
      #pragma unroll
      for (int n = 0; n < 4; n++) acc[m][n] = mfma_k32(af[m], bf[n], acc[m][n]);
    __syncthreads();
  }

  #pragma unroll
  for (int m = 0; m < 4; m++) {
    int row = bm + wr * 64 + m * 16 + lg * 4;
    #pragma unroll
    for (int n = 0; n < 4; n++) {
      int col = bn + wc * 64 + n * 16 + lr;
      #pragma unroll
      for (int r = 0; r < 4; r++)
        Out[(size_t)(row + r) * 512 + col] = acc[m][n][r];
    }
  }
}

// ---------------- fused attention: head-sequential, single exp pass ----------------
// Block = (b, 16 q-rows), 1024 thr = 16 waves; per head (sequential), wave w
// owns k-slice [w*128, w*128+128).  E per wave = 32 f16 (registers!) -> ONE
// QK^T + ONE exp per element.  other+mask staged once (66 KB LDS f16, shared
// by all 8 heads).  PV partials cross-wave reduced via red2 (67 KB LDS).
// 2 barriers per head.  K reg-double-buffered; V issued early in body; next
// head's Q prefetched under the reduce.  b = bid&3 -> K+V (4 MB) L2-resident.
#define LOADT(dst, base, st) {                                  \
    const f16* p_ = (base) + (size_t)(st) * 2048;               \
    dst##0 = *(const half8*)(p_);                               \
    dst##1 = *(const half8*)(p_ + 512);                         \
    dst##2 = *(const half8*)(p_ + 1024);                        \
    dst##3 = *(const half8*)(p_ + 1536); }

__global__ __launch_bounds__(1024) void attn_fused(
    const f16* __restrict__ Qp, const f16* __restrict__ Kfrag,
    const f16* __restrict__ Vfrag, const float* __restrict__ other,
    const unsigned char* __restrict__ mask8, const int* __restrict__ mask32,
    const unsigned int* __restrict__ flag, float* __restrict__ attn_out,
    f16* __restrict__ ctx) {
  __shared__ f16 othm[16][2056];      // masked, log2e-scaled f16  (65.8 KB)
  __shared__ float red[16][16];       // [wave][q] row-sum partials (1 KB)
  __shared__ float red2[16][16][66];  // [wave][q][dv] PV partials (67.6 KB)

  const int t = threadIdx.x;
  const int bid = blockIdx.x;
  const int b = bid & 3;
  const int qblk = (bid >> 2) * 16;
  const int w = t >> 6, ln = t & 63;
  const int lr = ln & 15, lg = ln >> 4;
  const bool use8 = (*flag) != 0;

  // ---- stage other+mask once: thread -> (q = t>>6, 32 k at (t&63)*32) ----
  {
    const int q = t >> 6, k0 = (t & 63) * 32;
    const size_t base = ((size_t)b * SS + qblk + q) * SS + k0;
    const float* op = other + base;
    if (use8) {
      const unsigned char* mp = mask8 + base;
      #pragma unroll
      for (int g = 0; g < 4; g++) {
        unsigned int mw0 = *(const unsigned int*)(mp + g * 8);
        unsigned int mw1 = *(const unsigned int*)(mp + g * 8 + 4);
        float4v o0 = *(const float4v*)(op + g * 8);
        float4v o1 = *(const float4v*)(op + g * 8 + 4);
        float4v r0, r1;
        #pragma unroll
        for (int r = 0; r < 4; r++) {
          r0[r] = ((mw0 >> (8 * r)) & 0xffu) ? MASKVAL : fmaf(o0[r], L2E, -EBIAS);
          r1[r] = ((mw1 >> (8 * r)) & 0xffu) ? MASKVAL : fmaf(o1[r], L2E, -EBIAS);
        }
        *(half8*)&othm[q][k0 + g * 8] = cvt8(r0, r1);
      }
    } else {
      const int* mp = mask32 + base;
      #pragma unroll
      for (int g = 0; g < 4; g++) {
        int4v m0 = *(const int4v*)(mp + g * 8);
        int4v m1 = *(const int4v*)(mp + g * 8 + 4);
        float4v o0 = *(const float4v*)(op + g * 8);
        float4v o1 = *(const float4v*)(op + g * 8 + 4);
        float4v r0, r1;
        #pragma unroll
        for (int r = 0; r < 4; r++) {
          r0[r] = m0[r] ? MASKVAL : fmaf(o0[r], L2E, -EBIAS);
          r1[r] = m1[r] ? MASKVAL : fmaf(o1[r], L2E, -EBIAS);
        }
        *(half8*)&othm[q][k0 + g * 8] = cvt8(r0, r1);
      }
    }
  }
  __syncthreads();

  const int q_g = qblk + lr;
  const f16* kfb = Kfrag + (size_t)(b * 8) * 131072 + ln * 8;
  const f16* vfb = Vfrag + (size_t)(b * 8) * 131072 + ln * 8;
  const f16* qpp = Qp + ((size_t)b * SS + q_g) * 512 + lg * 8;

  half8 qf0 = *(const half8*)(qpp);
  half8 qf1 = *(const half8*)(qpp + 32);

  half8 kA0, kA1, kA2, kA3, kB0, kB1, kB2, kB3;
  half8 vf0, vf1, vf2, vf3;

  LOADT(kA, kfb, w * 4 + 0);

  #define BODY(kf, edst, g) {                                             \
    float4v s0 = {}, s1 = {};                                             \
    s0 = mfma_k32(kf##0, qf0, s0);                                        \
    s0 = mfma_k32(kf##1, qf1, s0);                                        \
    s1 = mfma_k32(kf##2, qf0, s1);                                        \
    s1 = mfma_k32(kf##3, qf1, s1);                                        \
    const int kbase = w * 128 + (g) * 32;                                 \
    const half4 o40 = *(const half4*)&othm[lr][kbase + lg * 4];           \
    const half4 o41 = *(const half4*)&othm[lr][kbase + 16 + lg * 4];      \
    float4v ev0, ev1;                                                     \
    _Pragma("unroll")                                                     \
    for (int r = 0; r < 4; r++) {                                         \
      ev0[r] = exp2f(fmaf(s0[r], SCALE_L2E, (float)o40[r]));              \
      ev1[r] = exp2f(fmaf(s1[r], SCALE_L2E, (float)o41[r]));              \
    }                                                                     \
    rs += (ev0[0] + ev0[1]) + (ev0[2] + ev0[3]) +                         \
          (ev1[0] + ev1[1]) + (ev1[2] + ev1[3]);                          \
    edst = cvt8(ev0, ev1);                                                \
    cacc0 = mfma_k32(edst, vf0, cacc0);                                   \
    cacc1 = mfma_k32(edst, vf1, cacc1);                                   \
    cacc2 = mfma_k32(edst, vf2, cacc2);                                   \
    cacc3 = mfma_k32(edst, vf3, cacc3);                                   \
  }

  #define ASTORE(e, g) {                                                  \
    float4v av0, av1;                                                     \
    av0[0] = (float)e[0] * invl; av0[1] = (float)e[1] * invl;             \
    av0[2] = (float)e[2] * invl; av0[3] = (float)e[3] * invl;             \
    av1[0] = (float)e[4] * invl; av1[1] = (float)e[5] * invl;             \
    av1[2] = (float)e[6] * invl; av1[3] = (float)e[7] * invl;             \
    *(float4v*)(abase + (g) * 32 + lg * 4) = av0;                         \
    *(float4v*)(abase + (g) * 32 + 16 + lg * 4) = av1;                    \
  }

  for (int h = 0; h < 8; ++h) {
    const int bh = b * 8 + h;
    const f16* kfb_nx = (h < 7) ? kfb + 131072 : kfb;

    float rs = 0.f;
    float4v cacc0 = {}, cacc1 = {}, cacc2 = {}, cacc3 = {};
    half8 e0, e1, e2, e3;

    LOADT(vf, vfb, w * 4 + 0);
    LOADT(kB, kfb, w * 4 + 1);
    BODY(kA, e0, 0);

    LOADT(vf, vfb, w * 4 + 1);
    LOADT(kA, kfb, w * 4 + 2);
    BODY(kB, e1, 1);

    LOADT(vf, vfb, w * 4 + 2);
    LOADT(kB, kfb, w * 4 + 3);
    BODY(kA, e2, 2);

    LOADT(vf, vfb, w * 4 + 3);
    LOADT(kA, kfb_nx, w * 4 + 0);
    BODY(kB, e3, 3);

    // prefetch next head's Q (consumed after the barriers)
    const int hn = (h < 7) ? h + 1 : 7;
    half8 qn0 = *(const half8*)(qpp + hn * 64);
    half8 qn1 = *(const half8*)(qpp + hn * 64 + 32);

    // ---- cross-wave reductions ----
    rs += __shfl_xor(rs, 16);
    rs += __shfl_xor(rs, 32);
    if (ln < 16) red[w][lr] = rs;
    #pragma unroll
    for (int r = 0; r < 4; r++) {
      red2[w][lg * 4 + r][0 * 16 + lr] = cacc0[r];
      red2[w][lg * 4 + r][1 * 16 + lr] = cacc1[r];
      red2[w][lg * 4 + r][2 * 16 + lr] = cacc2[r];
      red2[w][lg * 4 + r][3 * 16 + lr] = cacc3[r];
    }
    __syncthreads();

    float lsum = 0.f;
    #pragma unroll
    for (int ww = 0; ww < 16; ww++) lsum += red[ww][lr];
    const float invl = 1.0f / lsum;

    float* abase = attn_out + ((size_t)bh * SS + q_g) * SS + w * 128;
    ASTORE(e0, 0);
    ASTORE(e1, 1);
    ASTORE(e2, 2);
    ASTORE(e3, 3);

    // ctx: wave w handles q-row w; lanes = dv
    {
      float s16 = 0.f, l2 = 0.f;
      #pragma unroll
      for (int ww = 0; ww < 16; ww++) {
        s16 += red2[ww][w][ln];
        l2 += red[ww][w];
      }
      ctx[((size_t)b * SS + qblk + w) * 512 + h * 64 + ln] = (f16)(s16 / l2);
    }
    __syncthreads();

    qf0 = qn0;
    qf1 = qn1;
    kfb = kfb_nx;
    vfb = (h < 7) ? vfb + 131072 : vfb;
  }
  #undef BODY
  #undef ASTORE
}

extern "C" void kernel_launch(void* const* d_in, const int* in_sizes, int n_in,
                              void* d_out, int out_size, void* d_ws, size_t ws_size,
                              hipStream_t stream) {
  const float* inQ   = (const float*)d_in[0];
  const float* inK   = (const float*)d_in[1];
  const float* inV   = (const float*)d_in[2];
  const void*  mask  = d_in[3];
  const float* other = (const float*)d_in[4];
  const float* WQ    = (const float*)d_in[5];
  const float* WK    = (const float*)d_in[6];
  const float* WV    = (const float*)d_in[7];
  const float* WF    = (const float*)d_in[8];

  char* ws = (char*)d_ws;
  size_t off = 0;
  unsigned int* flag = (unsigned int*)(ws + off); off += 256;
  f16* Qp    = (f16*)(ws + off); off += (size_t)MTOK * 512 * 2;
  f16* Kfrag = (f16*)(ws + off); off += (size_t)MTOK * 512 * 2;
  f16* Vfrag = (f16*)(ws + off); off += (size_t)MTOK * 512 * 2;
  f16* ctx   = (f16*)(ws + off); off += (size_t)MTOK * 512 * 2;
  if (ws_size < off) return;

  float* outp  = (float*)d_out;
  float* attnp = outp + (size_t)MTOK * DDIM;

  hipMemsetAsync(flag, 0, 256, stream);
  detect_mask_kernel<<<64, 256, 0, stream>>>((const unsigned int*)mask, flag);

  gemm_qkv<<<dim3(64, 4, 3), 256, 0, stream>>>(inQ, inK, inV, WQ, WK, WV,
                                               Qp, Kfrag, Vfrag);

  attn_fused<<<512, 1024, 0, stream>>>(
      Qp, Kfrag, Vfrag, other, (const unsigned char*)mask, (const int*)mask,
      flag, attnp, ctx);

  gemm_out<<<dim3(64, 4), 256, 0, stream>>>(ctx, WF, outp);
}